// Round 5
// baseline (92.792 us; speedup 1.0000x reference)
//
#include <hip/hip_runtime.h>
#include <math.h>

#define T_DIM 12
#define GRID_BLOCKS 1024

// One thread processes TWO adjacent columns (a = .x/.y, b = .z/.w of a float4).
// Arrays are (T, N, 2) f32 -> row stride in float4 units is N/2.
// All 24 float4 loads are staged to registers and PINNED above the compute
// with sched_barrier(0) for max memory-level parallelism; launch_bounds(256,4)
// raises the VGPR budget to 128 (16 waves/CU) to hold them.
// NO global atomics: per-block partials to distinct ws slots; kernel 2 reduces.
__global__ __launch_bounds__(256, 4) void ade_traj_kernel(
    const float4* __restrict__ inp,
    const float4* __restrict__ tgt,
    int npairs,                    // N/2
    float2* __restrict__ partials) // partials[blockIdx] = (num, cnt)
{
    const int stride = gridDim.x * blockDim.x;   // 262144
    float num = 0.0f;
    float cnt = 0.0f;

    for (int i = blockIdx.x * blockDim.x + threadIdx.x; i < npairs; i += stride) {
        // ---- stage ALL 24 loads (static indexing -> registers) ----
        float4 tv[T_DIM];
        float4 iv[T_DIM];
        #pragma unroll
        for (int t = 0; t < T_DIM; ++t) tv[t] = tgt[t * npairs + i];
        #pragma unroll
        for (int t = 0; t < T_DIM; ++t) iv[t] = inp[t * npairs + i];
        // pin: nothing moves across; all 24 loads issue before compute
        __builtin_amdgcn_sched_barrier(0);

        // ---- ADE ----
        float ade_a = 0.0f, ade_b = 0.0f;
        #pragma unroll
        for (int t = 0; t < T_DIM; ++t) {
            float dx = iv[t].x - tv[t].x, dy = iv[t].y - tv[t].y;
            ade_a += __builtin_amdgcn_sqrtf(dx * dx + dy * dy);
            float dxb = iv[t].z - tv[t].z, dyb = iv[t].w - tv[t].w;
            ade_b += __builtin_amdgcn_sqrtf(dxb * dxb + dyb * dyb);
        }

        // ---- Menger mask + run stats, sqrt/div-free:
        //      |k|>=1 <=> (2*area)^2 >= dist^2 ; NaN corner (0/0) -> mask 0.
        float run_a = 0.0f, mx_a = 0.0f, sm_a = 0.0f;
        float run_b = 0.0f, mx_b = 0.0f, sm_b = 0.0f;
        #pragma unroll
        for (int t = 2; t < T_DIM; ++t) {
            {
                float ax = tv[t-2].x, ay = tv[t-2].y;
                float bx = tv[t-1].x, by = tv[t-1].y;
                float cx = tv[t].x,   cy = tv[t].y;
                float ar = ax * (by - cy) + bx * (cy - ay) + cx * (ay - by);
                float a2 = 4.0f * ar * ar;
                float ex, ey;
                ex = bx - ax; ey = by - ay; float e01 = ex * ex + ey * ey;
                ex = cx - bx; ey = cy - by; float e12 = ex * ex + ey * ey;
                ex = cx - ax; ey = cy - ay; float e02 = ex * ex + ey * ey;
                float d2 = e01 * e12 * e02;
                float m = ((a2 >= d2) && !(d2 == 0.0f && a2 == 0.0f)) ? 1.0f : 0.0f;
                run_a += m;
                mx_a = fmaxf(mx_a, run_a);
                run_a *= m;
                sm_a += m;
            }
            {
                float ax = tv[t-2].z, ay = tv[t-2].w;
                float bx = tv[t-1].z, by = tv[t-1].w;
                float cx = tv[t].z,   cy = tv[t].w;
                float ar = ax * (by - cy) + bx * (cy - ay) + cx * (ay - by);
                float a2 = 4.0f * ar * ar;
                float ex, ey;
                ex = bx - ax; ey = by - ay; float e01 = ex * ex + ey * ey;
                ex = cx - bx; ey = cy - by; float e12 = ex * ex + ey * ey;
                ex = cx - ax; ey = cy - ay; float e02 = ex * ex + ey * ey;
                float d2 = e01 * e12 * e02;
                float m = ((a2 >= d2) && !(d2 == 0.0f && a2 == 0.0f)) ? 1.0f : 0.0f;
                run_b += m;
                mx_b = fmaxf(mx_b, run_b);
                run_b *= m;
                sm_b += m;
            }
        }

        bool sel_a = (mx_a >= 3.0f) && (sm_a > 0.0f);
        bool sel_b = (mx_b >= 3.0f) && (sm_b > 0.0f);
        if (sel_a) { num += ade_a * (1.0f / 12.0f); cnt += 1.0f; }
        if (sel_b) { num += ade_b * (1.0f / 12.0f); cnt += 1.0f; }
    }

    // wave(64) shuffle reduction
    #pragma unroll
    for (int off = 32; off > 0; off >>= 1) {
        num += __shfl_down(num, off, 64);
        cnt += __shfl_down(cnt, off, 64);
    }

    __shared__ float snum[4], scnt[4];
    const int wave = threadIdx.x >> 6;
    const int lane = threadIdx.x & 63;
    if (lane == 0) { snum[wave] = num; scnt[wave] = cnt; }
    __syncthreads();
    if (threadIdx.x == 0) {
        float n = 0.0f, c = 0.0f;
        #pragma unroll
        for (int w = 0; w < 4; ++w) { n += snum[w]; c += scnt[w]; }
        partials[blockIdx.x] = make_float2(n, c);   // plain store, unique slot
    }
}

__global__ __launch_bounds__(256) void ade_traj_finalize(
    const float2* __restrict__ partials, int g, float* __restrict__ out)
{
    float n = 0.0f, c = 0.0f;
    for (int j = threadIdx.x; j < g; j += 256) {
        float2 p = partials[j];
        n += p.x; c += p.y;
    }
    #pragma unroll
    for (int off = 32; off > 0; off >>= 1) {
        n += __shfl_down(n, off, 64);
        c += __shfl_down(c, off, 64);
    }
    __shared__ float sn[4], sc[4];
    const int wave = threadIdx.x >> 6;
    const int lane = threadIdx.x & 63;
    if (lane == 0) { sn[wave] = n; sc[wave] = c; }
    __syncthreads();
    if (threadIdx.x == 0) {
        float ns = 0.0f, cs = 0.0f;
        #pragma unroll
        for (int w = 0; w < 4; ++w) { ns += sn[w]; cs += sc[w]; }
        out[0] = (cs > 0.0f) ? (ns / fmaxf(cs, 1.0f)) : 0.0f;
    }
}

extern "C" void kernel_launch(void* const* d_in, const int* in_sizes, int n_in,
                              void* d_out, int out_size, void* d_ws, size_t ws_size,
                              hipStream_t stream) {
    const float* inp = (const float*)d_in[0];
    const float* tgt = (const float*)d_in[1];
    float* out = (float*)d_out;
    float2* partials = (float2*)d_ws;    // GRID_BLOCKS float2 slots, all written each launch

    const int total = in_sizes[0];       // T*N*2
    const int N = total / (T_DIM * 2);   // 1,500,000
    const int npairs = N / 2;            // 750,000

    ade_traj_kernel<<<GRID_BLOCKS, 256, 0, stream>>>(
        (const float4*)inp, (const float4*)tgt, npairs, partials);
    ade_traj_finalize<<<1, 256, 0, stream>>>(partials, GRID_BLOCKS, out);
}

// Round 6
// 56.710 us; speedup vs baseline: 1.6362x; 1.6362x over previous
//
#include <hip/hip_runtime.h>
#include <math.h>

#define T_DIM 12
#define GRID_BLOCKS 2048

// One thread processes TWO adjacent columns (a = .x/.y, b = .z/.w of a float4).
// Arrays are (T, N, 2) f32 -> row stride in float4 units is N/2.
// All 24 float4 loads staged to registers, pinned above compute via
// sched_barrier(0). NOTE: plain __launch_bounds__(256) — no min-waves arg.
// R5's (256,4) made the allocator cap at 64 VGPR and spill 82 MB to scratch;
// here the budget is 256 so ~96 staging regs fit (validity check: WRITE_SIZE
// must stay ~66 KB).
// NO global atomics: per-block partials to distinct ws slots; kernel 2 reduces.
__global__ __launch_bounds__(256) void ade_traj_kernel(
    const float4* __restrict__ inp,
    const float4* __restrict__ tgt,
    int npairs,                    // N/2
    float2* __restrict__ partials) // partials[blockIdx] = (num, cnt)
{
    const int stride = gridDim.x * blockDim.x;   // 524288
    float num = 0.0f;
    float cnt = 0.0f;

    for (int i = blockIdx.x * blockDim.x + threadIdx.x; i < npairs; i += stride) {
        // ---- stage ALL 24 loads (static indexing -> registers) ----
        float4 tv[T_DIM];
        float4 iv[T_DIM];
        #pragma unroll
        for (int t = 0; t < T_DIM; ++t) tv[t] = tgt[t * npairs + i];
        #pragma unroll
        for (int t = 0; t < T_DIM; ++t) iv[t] = inp[t * npairs + i];
        // pin: all 24 loads issue before any compute
        __builtin_amdgcn_sched_barrier(0);

        // ---- ADE ----
        float ade_a = 0.0f, ade_b = 0.0f;
        #pragma unroll
        for (int t = 0; t < T_DIM; ++t) {
            float dx = iv[t].x - tv[t].x, dy = iv[t].y - tv[t].y;
            ade_a += __builtin_amdgcn_sqrtf(dx * dx + dy * dy);
            float dxb = iv[t].z - tv[t].z, dyb = iv[t].w - tv[t].w;
            ade_b += __builtin_amdgcn_sqrtf(dxb * dxb + dyb * dyb);
        }

        // ---- Menger mask + run stats, sqrt/div-free:
        //      |k|>=1 <=> (2*area)^2 >= dist^2 ; NaN corner (0/0) -> mask 0.
        float run_a = 0.0f, mx_a = 0.0f, sm_a = 0.0f;
        float run_b = 0.0f, mx_b = 0.0f, sm_b = 0.0f;
        #pragma unroll
        for (int t = 2; t < T_DIM; ++t) {
            {
                float ax = tv[t-2].x, ay = tv[t-2].y;
                float bx = tv[t-1].x, by = tv[t-1].y;
                float cx = tv[t].x,   cy = tv[t].y;
                float ar = ax * (by - cy) + bx * (cy - ay) + cx * (ay - by);
                float a2 = 4.0f * ar * ar;
                float ex, ey;
                ex = bx - ax; ey = by - ay; float e01 = ex * ex + ey * ey;
                ex = cx - bx; ey = cy - by; float e12 = ex * ex + ey * ey;
                ex = cx - ax; ey = cy - ay; float e02 = ex * ex + ey * ey;
                float d2 = e01 * e12 * e02;
                float m = ((a2 >= d2) && !(d2 == 0.0f && a2 == 0.0f)) ? 1.0f : 0.0f;
                run_a += m;
                mx_a = fmaxf(mx_a, run_a);
                run_a *= m;
                sm_a += m;
            }
            {
                float ax = tv[t-2].z, ay = tv[t-2].w;
                float bx = tv[t-1].z, by = tv[t-1].w;
                float cx = tv[t].z,   cy = tv[t].w;
                float ar = ax * (by - cy) + bx * (cy - ay) + cx * (ay - by);
                float a2 = 4.0f * ar * ar;
                float ex, ey;
                ex = bx - ax; ey = by - ay; float e01 = ex * ex + ey * ey;
                ex = cx - bx; ey = cy - by; float e12 = ex * ex + ey * ey;
                ex = cx - ax; ey = cy - ay; float e02 = ex * ex + ey * ey;
                float d2 = e01 * e12 * e02;
                float m = ((a2 >= d2) && !(d2 == 0.0f && a2 == 0.0f)) ? 1.0f : 0.0f;
                run_b += m;
                mx_b = fmaxf(mx_b, run_b);
                run_b *= m;
                sm_b += m;
            }
        }

        bool sel_a = (mx_a >= 3.0f) && (sm_a > 0.0f);
        bool sel_b = (mx_b >= 3.0f) && (sm_b > 0.0f);
        if (sel_a) { num += ade_a * (1.0f / 12.0f); cnt += 1.0f; }
        if (sel_b) { num += ade_b * (1.0f / 12.0f); cnt += 1.0f; }
    }

    // wave(64) shuffle reduction
    #pragma unroll
    for (int off = 32; off > 0; off >>= 1) {
        num += __shfl_down(num, off, 64);
        cnt += __shfl_down(cnt, off, 64);
    }

    __shared__ float snum[4], scnt[4];
    const int wave = threadIdx.x >> 6;
    const int lane = threadIdx.x & 63;
    if (lane == 0) { snum[wave] = num; scnt[wave] = cnt; }
    __syncthreads();
    if (threadIdx.x == 0) {
        float n = 0.0f, c = 0.0f;
        #pragma unroll
        for (int w = 0; w < 4; ++w) { n += snum[w]; c += scnt[w]; }
        partials[blockIdx.x] = make_float2(n, c);   // plain store, unique slot
    }
}

__global__ __launch_bounds__(256) void ade_traj_finalize(
    const float2* __restrict__ partials, int g, float* __restrict__ out)
{
    float n = 0.0f, c = 0.0f;
    for (int j = threadIdx.x; j < g; j += 256) {
        float2 p = partials[j];
        n += p.x; c += p.y;
    }
    #pragma unroll
    for (int off = 32; off > 0; off >>= 1) {
        n += __shfl_down(n, off, 64);
        c += __shfl_down(c, off, 64);
    }
    __shared__ float sn[4], sc[4];
    const int wave = threadIdx.x >> 6;
    const int lane = threadIdx.x & 63;
    if (lane == 0) { sn[wave] = n; sc[wave] = c; }
    __syncthreads();
    if (threadIdx.x == 0) {
        float ns = 0.0f, cs = 0.0f;
        #pragma unroll
        for (int w = 0; w < 4; ++w) { ns += sn[w]; cs += sc[w]; }
        out[0] = (cs > 0.0f) ? (ns / fmaxf(cs, 1.0f)) : 0.0f;
    }
}

extern "C" void kernel_launch(void* const* d_in, const int* in_sizes, int n_in,
                              void* d_out, int out_size, void* d_ws, size_t ws_size,
                              hipStream_t stream) {
    const float* inp = (const float*)d_in[0];
    const float* tgt = (const float*)d_in[1];
    float* out = (float*)d_out;
    float2* partials = (float2*)d_ws;    // GRID_BLOCKS float2 slots, all written each launch

    const int total = in_sizes[0];       // T*N*2
    const int N = total / (T_DIM * 2);   // 1,500,000
    const int npairs = N / 2;            // 750,000

    ade_traj_kernel<<<GRID_BLOCKS, 256, 0, stream>>>(
        (const float4*)inp, (const float4*)tgt, npairs, partials);
    ade_traj_finalize<<<1, 256, 0, stream>>>(partials, GRID_BLOCKS, out);
}

// Round 7
// 52.997 us; speedup vs baseline: 1.7509x; 1.0701x over previous
//
#include <hip/hip_runtime.h>
#include <math.h>

#define T_DIM 12
#define GRID_BLOCKS 2048

// R4 revert — best measured config (52.7 us).
// One thread processes TWO adjacent columns (a = .x/.y, b = .z/.w of a float4).
// Arrays are (T, N, 2) f32 -> row stride in float4 units is N/2.
// Compiler-natural load/compute interleave at high occupancy (VGPR 40,
// ~32 waves/CU) beats forced register staging (R6: 31% occ, +4 us) and
// min-waves caps (R5: spill, +40 us).
// NO global atomics: per-block partials to distinct ws slots (plain store);
// kernel 2 reduces. Same-address device atomics were the R1-R3 bottleneck.
__global__ __launch_bounds__(256) void ade_traj_kernel(
    const float4* __restrict__ inp,
    const float4* __restrict__ tgt,
    int npairs,                    // N/2
    float2* __restrict__ partials) // partials[blockIdx] = (num, cnt)
{
    const int stride = gridDim.x * blockDim.x;
    float num = 0.0f;
    float cnt = 0.0f;

    for (int i = blockIdx.x * blockDim.x + threadIdx.x; i < npairs; i += stride) {
        float ade_a = 0.0f, ade_b = 0.0f;
        float run_a = 0.0f, mx_a = 0.0f, sm_a = 0.0f;
        float run_b = 0.0f, mx_b = 0.0f, sm_b = 0.0f;
        float p0ax = 0.f, p0ay = 0.f, p1ax = 0.f, p1ay = 0.f;
        float p0bx = 0.f, p0by = 0.f, p1bx = 0.f, p1by = 0.f;

        #pragma unroll
        for (int t = 0; t < T_DIM; ++t) {
            const int off = t * npairs + i;
            float4 tv = tgt[off];
            float4 iv = inp[off];

            // ADE contribution
            {
                float dx = iv.x - tv.x, dy = iv.y - tv.y;
                ade_a += __builtin_amdgcn_sqrtf(dx * dx + dy * dy);
                float dxb = iv.z - tv.z, dyb = iv.w - tv.w;
                ade_b += __builtin_amdgcn_sqrtf(dxb * dxb + dyb * dyb);
            }

            if (t >= 2) {
                // Menger mask, sqrt/div-free: |k|>=1 <=> (2*area)^2 >= dist^2.
                // NaN corner (0/0 -> k=NaN -> mask 0) handled explicitly;
                // inf corner (area>0, dist=0 -> mask 1) falls out of a2>=d2.
                {
                    float cx = tv.x, cy = tv.y;
                    float ar = p0ax * (p1ay - cy) + p1ax * (cy - p0ay) + cx * (p0ay - p1ay);
                    float a2 = 4.0f * ar * ar;
                    float ex, ey;
                    ex = p1ax - p0ax; ey = p1ay - p0ay; float e01 = ex * ex + ey * ey;
                    ex = cx - p1ax;   ey = cy - p1ay;   float e12 = ex * ex + ey * ey;
                    ex = cx - p0ax;   ey = cy - p0ay;   float e02 = ex * ex + ey * ey;
                    float d2 = e01 * e12 * e02;
                    float m = ((a2 >= d2) && !(d2 == 0.0f && a2 == 0.0f)) ? 1.0f : 0.0f;
                    run_a += m;
                    mx_a = fmaxf(mx_a, run_a);
                    run_a *= m;
                    sm_a += m;
                }
                {
                    float cx = tv.z, cy = tv.w;
                    float ar = p0bx * (p1by - cy) + p1bx * (cy - p0by) + cx * (p0by - p1by);
                    float a2 = 4.0f * ar * ar;
                    float ex, ey;
                    ex = p1bx - p0bx; ey = p1by - p0by; float e01 = ex * ex + ey * ey;
                    ex = cx - p1bx;   ey = cy - p1by;   float e12 = ex * ex + ey * ey;
                    ex = cx - p0bx;   ey = cy - p0by;   float e02 = ex * ex + ey * ey;
                    float d2 = e01 * e12 * e02;
                    float m = ((a2 >= d2) && !(d2 == 0.0f && a2 == 0.0f)) ? 1.0f : 0.0f;
                    run_b += m;
                    mx_b = fmaxf(mx_b, run_b);
                    run_b *= m;
                    sm_b += m;
                }
            }
            p0ax = p1ax; p0ay = p1ay; p1ax = tv.x; p1ay = tv.y;
            p0bx = p1bx; p0by = p1by; p1bx = tv.z; p1by = tv.w;
        }

        // criteria = (mx>=3) & (mx<11) & (sm>0); mx<=10 so (mx<11) vacuous
        bool sel_a = (mx_a >= 3.0f) && (sm_a > 0.0f);
        bool sel_b = (mx_b >= 3.0f) && (sm_b > 0.0f);
        if (sel_a) { num += ade_a * (1.0f / 12.0f); cnt += 1.0f; }
        if (sel_b) { num += ade_b * (1.0f / 12.0f); cnt += 1.0f; }
    }

    // wave(64) shuffle reduction
    #pragma unroll
    for (int off = 32; off > 0; off >>= 1) {
        num += __shfl_down(num, off, 64);
        cnt += __shfl_down(cnt, off, 64);
    }

    __shared__ float snum[4], scnt[4];
    const int wave = threadIdx.x >> 6;
    const int lane = threadIdx.x & 63;
    if (lane == 0) { snum[wave] = num; scnt[wave] = cnt; }
    __syncthreads();
    if (threadIdx.x == 0) {
        float n = 0.0f, c = 0.0f;
        #pragma unroll
        for (int w = 0; w < 4; ++w) { n += snum[w]; c += scnt[w]; }
        partials[blockIdx.x] = make_float2(n, c);   // plain store, unique slot
    }
}

__global__ __launch_bounds__(256) void ade_traj_finalize(
    const float2* __restrict__ partials, int g, float* __restrict__ out)
{
    float n = 0.0f, c = 0.0f;
    for (int j = threadIdx.x; j < g; j += 256) {
        float2 p = partials[j];
        n += p.x; c += p.y;
    }
    #pragma unroll
    for (int off = 32; off > 0; off >>= 1) {
        n += __shfl_down(n, off, 64);
        c += __shfl_down(c, off, 64);
    }
    __shared__ float sn[4], sc[4];
    const int wave = threadIdx.x >> 6;
    const int lane = threadIdx.x & 63;
    if (lane == 0) { sn[wave] = n; sc[wave] = c; }
    __syncthreads();
    if (threadIdx.x == 0) {
        float ns = 0.0f, cs = 0.0f;
        #pragma unroll
        for (int w = 0; w < 4; ++w) { ns += sn[w]; cs += sc[w]; }
        out[0] = (cs > 0.0f) ? (ns / fmaxf(cs, 1.0f)) : 0.0f;
    }
}

extern "C" void kernel_launch(void* const* d_in, const int* in_sizes, int n_in,
                              void* d_out, int out_size, void* d_ws, size_t ws_size,
                              hipStream_t stream) {
    const float* inp = (const float*)d_in[0];
    const float* tgt = (const float*)d_in[1];
    float* out = (float*)d_out;
    float2* partials = (float2*)d_ws;    // GRID_BLOCKS float2 slots, all written each launch

    const int total = in_sizes[0];       // T*N*2
    const int N = total / (T_DIM * 2);   // 1,500,000
    const int npairs = N / 2;            // 750,000

    ade_traj_kernel<<<GRID_BLOCKS, 256, 0, stream>>>(
        (const float4*)inp, (const float4*)tgt, npairs, partials);
    ade_traj_finalize<<<1, 256, 0, stream>>>(partials, GRID_BLOCKS, out);
}